// Round 4
// baseline (3963.207 us; speedup 1.0000x reference)
//
#include <hip/hip_runtime.h>

typedef unsigned short u16;
typedef unsigned int u32;
typedef unsigned long long u64;
typedef short v8s __attribute__((ext_vector_type(8)));
typedef float v4f __attribute__((ext_vector_type(4)));

#define NN 4096
#define BATCH 32

__device__ __forceinline__ float b2f(u16 u) {
  union { u32 i; float f; } c; c.i = ((u32)u) << 16; return c.f;
}
__device__ __forceinline__ u16 f2b(float f) {
  union { float f; u32 i; } c; c.f = f;
  u32 x = c.i;
  return (u16)((x + 0x7fffu + ((x >> 16) & 1u)) >> 16);
}
__device__ __forceinline__ u32 pk2(float a, float b) {
  return (u32)f2b(a) | ((u32)f2b(b) << 16);
}

// ---------------------------------------------------------------------------
// S-GEMM: C[m][c] = sum_k A[m][k] * B[c][k];  writes C^T: Ct[c][m]
// A is FLOAT32 (the S matrices), converted to bf16 during LDS staging.
// B (workspace features) is bf16. Optional Chebyshev: Ct = 2*acc - Xt.
// grid: (M/128, C/128), block 256.
// ---------------------------------------------------------------------------
__global__ __launch_bounds__(256) void gemm_s(const float* __restrict__ A,
                                              const u16* __restrict__ B,
                                              u16* __restrict__ Ct,
                                              const u16* __restrict__ Xt) {
  __shared__ __align__(16) u16 As[4096];   // 128 m x 32 k
  __shared__ __align__(16) u16 Bs[4096];   // 128 c x 32 k
  __shared__ __align__(16) u16 T[16384];   // 128 c x 128 m
  const int t = threadIdx.x;
  const int wave = t >> 6, lane = t & 63;
  const int m0 = blockIdx.x << 7, c0 = blockIdx.y << 7;
  const int wm = (wave >> 1) << 6, wc = (wave & 1) << 6;
  const int q = lane >> 4, r16 = lane & 15;
  v4f acc[4][4];
  const v4f vz = {0.f, 0.f, 0.f, 0.f};
#pragma unroll
  for (int i = 0; i < 4; ++i)
#pragma unroll
    for (int j = 0; j < 4; ++j) acc[i][j] = vz;

  const int sr = t >> 2;             // 0..63
  const int sc = (t & 3) << 3;       // 0,8,16,24 (elements)
  const u64 abase = (u64)(m0 + sr) * NN + sc;   // float index
  const u64 bbase = (u64)(c0 + sr) * NN + sc;   // u16 index
  const u64 rstep = (u64)64 * NN;
  u16* as0 = As + sr * 32 + sc;
  u16* as1 = As + (64 + sr) * 32 + sc;
  u16* bs0 = Bs + sr * 32 + sc;
  u16* bs1 = Bs + (64 + sr) * 32 + sc;

  for (int k0 = 0; k0 < NN; k0 += 32) {
    const float4 a0l = *(const float4*)(A + abase + k0);
    const float4 a0h = *(const float4*)(A + abase + k0 + 4);
    const float4 a1l = *(const float4*)(A + abase + rstep + k0);
    const float4 a1h = *(const float4*)(A + abase + rstep + k0 + 4);
    const uint4 b0 = *(const uint4*)(B + bbase + k0);
    const uint4 b1 = *(const uint4*)(B + bbase + rstep + k0);
    uint4 pa0, pa1;
    pa0.x = pk2(a0l.x, a0l.y); pa0.y = pk2(a0l.z, a0l.w);
    pa0.z = pk2(a0h.x, a0h.y); pa0.w = pk2(a0h.z, a0h.w);
    pa1.x = pk2(a1l.x, a1l.y); pa1.y = pk2(a1l.z, a1l.w);
    pa1.z = pk2(a1h.x, a1h.y); pa1.w = pk2(a1h.z, a1h.w);
    __syncthreads();                  // prev-iter readers done before overwrite
    *(uint4*)as0 = pa0;
    *(uint4*)as1 = pa1;
    *(uint4*)bs0 = b0;
    *(uint4*)bs1 = b1;
    __syncthreads();
    v8s af[4], bf[4];
#pragma unroll
    for (int i = 0; i < 4; ++i)
      af[i] = *(const v8s*)(As + ((wm + i * 16 + r16) << 5) + (q << 3));
#pragma unroll
    for (int j = 0; j < 4; ++j)
      bf[j] = *(const v8s*)(Bs + ((wc + j * 16 + r16) << 5) + (q << 3));
#pragma unroll
    for (int i = 0; i < 4; ++i)
#pragma unroll
      for (int j = 0; j < 4; ++j)
        acc[i][j] = __builtin_amdgcn_mfma_f32_16x16x32_bf16(af[i], bf[j], acc[i][j], 0, 0, 0);
  }

  // epilogue: acc (C[m][c] fragments) -> T[c][m] -> global (c-major rows)
#pragma unroll
  for (int i = 0; i < 4; ++i)
#pragma unroll
    for (int j = 0; j < 4; ++j) {
      const int cl = wc + j * 16 + r16;          // 0..127
      const int mm = wm + i * 16 + (q << 2);     // 0..124, step 4
      uint2 pv;
      pv.x = pk2(acc[i][j][0], acc[i][j][1]);
      pv.y = pk2(acc[i][j][2], acc[i][j][3]);
      *(uint2*)(T + (cl << 7) + mm) = pv;
    }
  __syncthreads();
#pragma unroll
  for (int it = 0; it < 8; ++it) {
    const int flat = it * 256 + t;
    const int cl = flat >> 4;                    // 0..127
    const int seg = (flat & 15) << 3;            // 0..120
    const u64 gi = (u64)(c0 + cl) * NN + m0 + seg;
    union { uint4 v; u16 e[8]; } tv;
    tv.v = *(uint4*)(T + (cl << 7) + seg);
    if (Xt) {
      union { uint4 v; u16 e[8]; } xv, ov;
      xv.v = *(const uint4*)(Xt + gi);
#pragma unroll
      for (int s = 0; s < 8; ++s) ov.e[s] = f2b(2.f * b2f(tv.e[s]) - b2f(xv.e[s]));
      *(uint4*)(Ct + gi) = ov.v;
    } else {
      *(uint4*)(Ct + gi) = tv.v;
    }
  }
}

// ---------------------------------------------------------------------------
// Projection: out[b*JSTR + j][n] = act( sum_k Wt[j][k] * F[row(k,b)][n] + b[j] )
// row(k,b) = i*(32*DP) + b*DP + d  with i=k/DP, d=k%DP.  bias is f32.
// grid: (4096/128, Jblocks, 32). ACT: 0 sigmoid, 1 tanh.
// ---------------------------------------------------------------------------
template <int DP, int KTOT>
__global__ __launch_bounds__(256) void proj_k(const u16* __restrict__ Wt,
                                              const u16* __restrict__ F,
                                              const float* __restrict__ bias,
                                              u16* __restrict__ outp,
                                              const int JSTR, const int ACT) {
  __shared__ __align__(16) u16 As2[2048];  // 64 j x 32 k
  __shared__ __align__(16) u16 Bs2[4096];  // 32 k x 128 n
  const int t = threadIdx.x;
  const int wave = t >> 6, lane = t & 63;
  const int q = lane >> 4, r16 = lane & 15;
  const int n0 = blockIdx.x << 7;
  const int j0 = blockIdx.y << 6;
  const int b = blockIdx.z;
  v4f acc[4][2];
  const v4f vz = {0.f, 0.f, 0.f, 0.f};
#pragma unroll
  for (int i = 0; i < 4; ++i) { acc[i][0] = vz; acc[i][1] = vz; }

  const int ar = t >> 2, ac = (t & 3) << 3;      // A stage: row 0..63, chunk
  const u64 wbase = (u64)(j0 + ar) * KTOT + ac;

  for (int k0 = 0; k0 < KTOT; k0 += 32) {
    const uint4 av = *(const uint4*)(Wt + wbase + k0);
    uint4 bv[2];
#pragma unroll
    for (int ci = 0; ci < 2; ++ci) {
      const int c = ci * 256 + t;
      const int kr = c >> 4;                     // 0..31
      const int seg = (c & 15) << 3;             // 0..120
      const int kk = k0 + kr;
      const int i = kk / DP;
      const int d = kk - i * DP;
      bv[ci] = *(const uint4*)(F + ((u64)i * (BATCH * DP) + (u64)b * DP + d) * NN + n0 + seg);
    }
    __syncthreads();
    *(uint4*)(As2 + ar * 32 + ac) = av;
#pragma unroll
    for (int ci = 0; ci < 2; ++ci) {
      const int c = ci * 256 + t;
      const int kr = c >> 4;
      const int seg = (c & 15) << 3;
      *(uint4*)(Bs2 + (kr << 7) + seg) = bv[ci];
    }
    __syncthreads();
    v8s af[4], bf[2];
#pragma unroll
    for (int i = 0; i < 4; ++i)
      af[i] = *(const v8s*)(As2 + ((i * 16 + r16) << 5) + (q << 3));
#pragma unroll
    for (int jj = 0; jj < 2; ++jj) {
      const int nn = (wave << 5) + jj * 16 + r16;
      v8s v;
#pragma unroll
      for (int s = 0; s < 8; ++s) v[s] = (short)Bs2[(((q << 3) + s) << 7) + nn];
      bf[jj] = v;
    }
#pragma unroll
    for (int i = 0; i < 4; ++i)
#pragma unroll
      for (int jj = 0; jj < 2; ++jj)
        acc[i][jj] = __builtin_amdgcn_mfma_f32_16x16x32_bf16(af[i], bf[jj], acc[i][jj], 0, 0, 0);
  }
#pragma unroll
  for (int i = 0; i < 4; ++i)
#pragma unroll
    for (int jj = 0; jj < 2; ++jj)
#pragma unroll
      for (int r = 0; r < 4; ++r) {
        const int j = j0 + i * 16 + (q << 2) + r;
        const int n = n0 + (wave << 5) + jj * 16 + r16;
        float v = acc[i][jj][r] + bias[j];
        v = ACT ? (1.f - 2.f / (__expf(2.f * v) + 1.f)) : (1.f / (1.f + __expf(-v)));
        outp[((u64)b * JSTR + j) * NN + n] = f2b(v);
      }
}

// ---------------------------------------------------------------------------
// Weight repack: Wt[j][i*DP+d] = bf16(W[i*D+d][j]), zero-padded. W is f32.
// ---------------------------------------------------------------------------
__global__ __launch_bounds__(256) void repackW(const float* __restrict__ W, u16* __restrict__ Wt,
                                               const int D, const int DP, const int KTOT,
                                               const int J) {
  const int idx = blockIdx.x * 256 + threadIdx.x;
  if (idx >= J * KTOT) return;
  const int j = idx / KTOT, k = idx - j * KTOT;
  const int i = k / DP, d = k - i * DP;
  u16 v = 0;
  if (i < 5 && d < D) v = f2b(W[(i * D + d) * J + j]);
  Wt[idx] = v;
}

// ---------------------------------------------------------------------------
// pack0: F0[b*72 + 0][n]=x[b][n]; F0[b*72+1+d][n]=h0[b][n][d]; rows 65..71 = 0
// x, hid0 are f32. grid (64 ntiles, 32 b), block 256.
// ---------------------------------------------------------------------------
__global__ __launch_bounds__(256) void pack0(const float* __restrict__ x,
                                             const float* __restrict__ hid0,
                                             u16* __restrict__ F0) {
  __shared__ __align__(16) u16 Hs[64 * 72];
  const int b = blockIdx.y, n0 = blockIdx.x << 6, t = threadIdx.x;
  const int r = t >> 2, ds = t & 3;
  const float* hrow = hid0 + ((u64)b * NN + n0 + r) * 64;
#pragma unroll
  for (int c4 = 0; c4 < 4; ++c4) {
    const float4 v = *(const float4*)(hrow + ds * 16 + c4 * 4);
    uint2 p;
    p.x = pk2(v.x, v.y);
    p.y = pk2(v.z, v.w);
    *(uint2*)(Hs + r * 72 + ds * 16 + c4 * 4) = p;
  }
  __syncthreads();
#pragma unroll
  for (int c2 = 0; c2 < 2; ++c2) {
    union { uint4 v; u16 h[8]; } o;
#pragma unroll
    for (int s = 0; s < 8; ++s) o.h[s] = Hs[(ds * 16 + c2 * 8 + s) * 72 + r];
    *(uint4*)(F0 + ((u64)b * 72 + 1 + r) * NN + n0 + ds * 16 + c2 * 8) = o.v;
  }
  if (t < 64) {
    F0[(u64)b * 72 * NN + n0 + t] = f2b(x[(u64)b * NN + n0 + t]);
  } else if (t < 120) {
    const int tt = t - 64;
    const int row = 65 + (tt >> 3), seg = (tt & 7) << 3;
    uint4 z; z.x = z.y = z.z = z.w = 0;
    *(uint4*)(F0 + ((u64)b * 72 + row) * NN + n0 + seg) = z;
  }
}

// ---------------------------------------------------------------------------
// pack1: F1[b*128+64+d][n] = bf16(h1[b][n][d])  (h-rows only). h1 is f32.
// ---------------------------------------------------------------------------
__global__ __launch_bounds__(256) void pack1(const float* __restrict__ hid1,
                                             u16* __restrict__ F1) {
  __shared__ __align__(16) u16 Hs[64 * 72];
  const int b = blockIdx.y, n0 = blockIdx.x << 6, t = threadIdx.x;
  const int r = t >> 2, ds = t & 3;
  const float* hrow = hid1 + ((u64)b * NN + n0 + r) * 64;
#pragma unroll
  for (int c4 = 0; c4 < 4; ++c4) {
    const float4 v = *(const float4*)(hrow + ds * 16 + c4 * 4);
    uint2 p;
    p.x = pk2(v.x, v.y);
    p.y = pk2(v.z, v.w);
    *(uint2*)(Hs + r * 72 + ds * 16 + c4 * 4) = p;
  }
  __syncthreads();
#pragma unroll
  for (int c2 = 0; c2 < 2; ++c2) {
    union { uint4 v; u16 h[8]; } o;
#pragma unroll
    for (int s = 0; s < 8; ++s) o.h[s] = Hs[(ds * 16 + c2 * 8 + s) * 72 + r];
    *(uint4*)(F1 + ((u64)b * 128 + 64 + r) * NN + n0 + ds * 16 + c2 * 8) = o.v;
  }
}

// ---------------------------------------------------------------------------
// candpack: F[b*DP + OFF + d][n] *= r  where r = G[b*128+d][n]  (in-place)
// ---------------------------------------------------------------------------
__global__ __launch_bounds__(256) void candpack(const u16* __restrict__ G, u16* __restrict__ F,
                                                const int DP, const int OFF) {
  const int u = blockIdx.x * 256 + threadIdx.x;
  const int b = u >> 15;
  const int d = (u >> 9) & 63;
  const int seg = (u & 511) << 3;
  union { uint4 v; u16 h[8]; } g, f, o;
  g.v = *(const uint4*)(G + ((u64)b * 128 + d) * NN + seg);
  u16* fp = F + ((u64)b * DP + OFF + d) * NN + seg;
  f.v = *(const uint4*)fp;
#pragma unroll
  for (int s = 0; s < 8; ++s) o.h[s] = f2b(b2f(f.h[s]) * b2f(g.h[s]));
  *(uint4*)fp = o.v;
}

// ---------------------------------------------------------------------------
// hnew: h' = u*h + (1-u)*c with u = G[b*128+64+d], c = G[b*128+d].
// hidL is f32. Writes HnF[b*128+d][n] (bf16, F slot-0 rows for next layer)
// and outH[b][n][d] (f32, d_out).  grid (64 ntiles, 32 b).
// ---------------------------------------------------------------------------
__global__ __launch_bounds__(256) void hnew_k(const u16* __restrict__ G,
                                              const float* __restrict__ hidL,
                                              u16* __restrict__ HnF,
                                              float* __restrict__ outH) {
  __shared__ __align__(16) float Hs[64 * 72];
  __shared__ __align__(16) float T2[64 * 72];
  const int b = blockIdx.y, n0 = blockIdx.x << 6, t = threadIdx.x;
  const int r = t >> 2, ds = t & 3;
  const float* hrow = hidL + ((u64)b * NN + n0 + r) * 64;
#pragma unroll
  for (int c4 = 0; c4 < 4; ++c4)
    *(float4*)(Hs + r * 72 + ds * 16 + c4 * 4) = *(const float4*)(hrow + ds * 16 + c4 * 4);
  __syncthreads();
#pragma unroll
  for (int c2 = 0; c2 < 2; ++c2) {
    const int ncol = ds * 16 + c2 * 8;
    union { uint4 v; u16 h[8]; } uv, cv, o;
    uv.v = *(const uint4*)(G + ((u64)b * 128 + 64 + r) * NN + n0 + ncol);
    cv.v = *(const uint4*)(G + ((u64)b * 128 + r) * NN + n0 + ncol);
#pragma unroll
    for (int s = 0; s < 8; ++s) {
      const int nl = ncol + s;
      const float uu = b2f(uv.h[s]);
      const float hh = Hs[nl * 72 + r];
      const float cc = b2f(cv.h[s]);
      const float v = uu * hh + (1.f - uu) * cc;
      o.h[s] = f2b(v);
      T2[nl * 72 + r] = v;
    }
    *(uint4*)(HnF + ((u64)b * 128 + r) * NN + n0 + ncol) = o.v;
  }
  __syncthreads();
  const int nl2 = t >> 2, dseg = (t & 3) << 4;
#pragma unroll
  for (int c4 = 0; c4 < 4; ++c4) {
    const float4 v = *(const float4*)(T2 + nl2 * 72 + dseg + c4 * 4);
    *(float4*)(outH + ((u64)b * NN + n0 + nl2) * 64 + dseg + c4 * 4) = v;
  }
}

// ---------------------------------------------------------------------------
// predict: out[b*4096+n] = sum_d H1[(b*4096+n)*64+d]*Wp[d] + bp  (all f32)
// ---------------------------------------------------------------------------
__global__ __launch_bounds__(256) void predictk(const float* __restrict__ H1bnd,
                                                const float* __restrict__ Wp,
                                                const float* __restrict__ bp,
                                                float* __restrict__ outp) {
  __shared__ float w[64];
  __shared__ float bb;
  const int t = threadIdx.x;
  if (t < 64) w[t] = Wp[t];
  if (t == 64) bb = bp[0];
  __syncthreads();
  const int idx = blockIdx.x * 256 + t;
  const float* h = H1bnd + (u64)idx * 64;
  float acc = bb;
#pragma unroll
  for (int c4 = 0; c4 < 16; ++c4) {
    const float4 v = *(const float4*)(h + c4 * 4);
    acc += v.x * w[c4 * 4] + v.y * w[c4 * 4 + 1] + v.z * w[c4 * 4 + 2] + v.w * w[c4 * 4 + 3];
  }
  outp[idx] = acc;
}

extern "C" void kernel_launch(void* const* d_in, const int* in_sizes, int n_in,
                              void* d_out, int out_size, void* d_ws, size_t ws_size,
                              hipStream_t stream) {
  const float* X   = (const float*)d_in[0];
  const float* HID = (const float*)d_in[1];
  const float* Sf  = (const float*)d_in[2];
  const float* Sb  = (const float*)d_in[3];
  const float* Wg0 = (const float*)d_in[4];
  const float* bg0 = (const float*)d_in[5];
  const float* Wc0 = (const float*)d_in[6];
  const float* bc0 = (const float*)d_in[7];
  const float* Wg1 = (const float*)d_in[8];
  const float* bg1 = (const float*)d_in[9];
  const float* Wc1 = (const float*)d_in[10];
  const float* bc1 = (const float*)d_in[11];
  const float* Wp  = (const float*)d_in[12];
  const float* bp  = (const float*)d_in[13];
  float* OUT = (float*)d_out;
  char* ws = (char*)d_ws;

  // workspace map (bytes), total ~192.4 MiB (internal bf16):
  //   F  : 20480 rows x 4096 bf16 = 167,772,160 B
  //   G  : 32 x 128 x 4096 bf16   =  33,554,432 B
  //   WT : repacked weights       =     393,216 B
  u16* F  = (u16*)(ws);
  u16* G  = (u16*)(ws + 167772160ull);
  u16* WT = (u16*)(ws + 167772160ull + 33554432ull);
  u16* Wg0t = WT;                   // 128 x 384
  u16* Wc0t = Wg0t + 128 * 384;     // 64 x 384
  u16* Wg1t = Wc0t + 64 * 384;      // 128 x 640
  u16* Wc1t = Wg1t + 128 * 640;     // 64 x 640

  const float* HID1 = HID + (u64)32 * 4096 * 64;
  float* OUT_H0 = OUT + 131072;
  float* OUT_H1 = OUT + 131072 + 8388608;

  // zero the layer-0 K-padding region of F (rows 11520..13823), read by proj i=5
  hipMemsetAsync(ws + (u64)11520 * NN * 2, 0, (u64)2304 * NN * 2, stream);

  repackW<<<(128 * 384 + 255) / 256, 256, 0, stream>>>(Wg0, Wg0t, 65, 72, 384, 128);
  repackW<<<(64 * 384 + 255) / 256, 256, 0, stream>>>(Wc0, Wc0t, 65, 72, 384, 64);
  repackW<<<(128 * 640 + 255) / 256, 256, 0, stream>>>(Wg1, Wg1t, 128, 128, 640, 128);
  repackW<<<(64 * 640 + 255) / 256, 256, 0, stream>>>(Wc1, Wc1t, 128, 128, 640, 64);

  // ---------------- layer 0 (Dp=72, C=2304) ----------------
  pack0<<<dim3(64, 32), 256, 0, stream>>>(X, HID, F);
  const u64 R0 = (u64)2304 * NN;
  dim3 gs0(32, 18);
  gemm_s<<<gs0, 256, 0, stream>>>(Sf, F, F + R0, nullptr);            // x1f
  gemm_s<<<gs0, 256, 0, stream>>>(Sb, F, F + 3 * R0, nullptr);        // x1b
  gemm_s<<<gs0, 256, 0, stream>>>(Sf, F + R0, F + 2 * R0, F);         // x2f
  gemm_s<<<gs0, 256, 0, stream>>>(Sb, F + 3 * R0, F + 4 * R0, F);     // x2b
  proj_k<72, 384><<<dim3(32, 2, 32), 256, 0, stream>>>(Wg0t, F, bg0, G, 128, 0);
  candpack<<<4096, 256, 0, stream>>>(G, F, 72, 1);                    // X0 <- [x | r*h]
  gemm_s<<<gs0, 256, 0, stream>>>(Sf, F, F + R0, nullptr);
  gemm_s<<<gs0, 256, 0, stream>>>(Sb, F, F + 3 * R0, nullptr);
  gemm_s<<<gs0, 256, 0, stream>>>(Sf, F + R0, F + 2 * R0, F);
  gemm_s<<<gs0, 256, 0, stream>>>(Sb, F + 3 * R0, F + 4 * R0, F);
  proj_k<72, 384><<<dim3(32, 1, 32), 256, 0, stream>>>(Wc0t, F, bc0, G, 128, 1);
  hnew_k<<<dim3(64, 32), 256, 0, stream>>>(G, HID, F, OUT_H0);        // F rows b*128+d

  // ---------------- layer 1 (Dp=128, C=4096) ----------------
  pack1<<<dim3(64, 32), 256, 0, stream>>>(HID1, F);                   // F rows b*128+64+d
  const u64 R1 = (u64)4096 * NN;
  dim3 gs1(32, 32);
  gemm_s<<<gs1, 256, 0, stream>>>(Sf, F, F + R1, nullptr);
  gemm_s<<<gs1, 256, 0, stream>>>(Sb, F, F + 3 * R1, nullptr);
  gemm_s<<<gs1, 256, 0, stream>>>(Sf, F + R1, F + 2 * R1, F);
  gemm_s<<<gs1, 256, 0, stream>>>(Sb, F + 3 * R1, F + 4 * R1, F);
  proj_k<128, 640><<<dim3(32, 2, 32), 256, 0, stream>>>(Wg1t, F, bg1, G, 128, 0);
  candpack<<<4096, 256, 0, stream>>>(G, F, 128, 64);
  gemm_s<<<gs1, 256, 0, stream>>>(Sf, F, F + R1, nullptr);
  gemm_s<<<gs1, 256, 0, stream>>>(Sb, F, F + 3 * R1, nullptr);
  gemm_s<<<gs1, 256, 0, stream>>>(Sf, F + R1, F + 2 * R1, F);
  gemm_s<<<gs1, 256, 0, stream>>>(Sb, F + 3 * R1, F + 4 * R1, F);
  proj_k<128, 640><<<dim3(32, 1, 32), 256, 0, stream>>>(Wc1t, F, bc1, G, 128, 1);
  hnew_k<<<dim3(64, 32), 256, 0, stream>>>(G, HID1, F, OUT_H1);

  predictk<<<512, 256, 0, stream>>>(OUT_H1, Wp, bp, OUT);
}

// Round 5
// 2755.379 us; speedup vs baseline: 1.4384x; 1.4384x over previous
//
#include <hip/hip_runtime.h>

typedef unsigned short u16;
typedef unsigned int u32;
typedef unsigned long long u64;
typedef short v8s __attribute__((ext_vector_type(8)));
typedef float v4f __attribute__((ext_vector_type(4)));

#define NN 4096
#define BATCH 32

__device__ __forceinline__ float b2f(u16 u) {
  union { u32 i; float f; } c; c.i = ((u32)u) << 16; return c.f;
}
__device__ __forceinline__ u16 f2b(float f) {
  union { float f; u32 i; } c; c.f = f;
  u32 x = c.i;
  return (u16)((x + 0x7fffu + ((x >> 16) & 1u)) >> 16);
}
__device__ __forceinline__ u32 pk2(float a, float b) {
  return (u32)f2b(a) | ((u32)f2b(b) << 16);
}

typedef const __attribute__((address_space(1))) u32* gp_t;
typedef __attribute__((address_space(3))) u32* lp_t;
__device__ __forceinline__ void gld16(const u16* g, u16* l) {
  __builtin_amdgcn_global_load_lds((gp_t)g, (lp_t)l, 16, 0, 0);
}

// ---------------------------------------------------------------------------
// cvtS: f32 -> bf16 (RNE), 8 elems/thread. grid: 8192 x 256 for 16.8M elems.
// ---------------------------------------------------------------------------
__global__ __launch_bounds__(256) void cvtS(const float* __restrict__ S,
                                            u16* __restrict__ Sb) {
  const u64 idx = ((u64)blockIdx.x * 256 + threadIdx.x) * 8;
  const float4 a = *(const float4*)(S + idx);
  const float4 b = *(const float4*)(S + idx + 4);
  uint4 o;
  o.x = pk2(a.x, a.y); o.y = pk2(a.z, a.w);
  o.z = pk2(b.x, b.y); o.w = pk2(b.z, b.w);
  *(uint4*)(Sb + idx) = o;
}

// ---------------------------------------------------------------------------
// gemm_sb: A bf16 (pre-converted S), B bf16. global_load_lds staging, 16 KB LDS.
// C[m][c] = sum_k A[m][k]*B[c][k]; writes Ct[c][m]; optional 2*acc - Xt.
// grid: (M/128, C/128), block 256.
// ---------------------------------------------------------------------------
__global__ __launch_bounds__(256) void gemm_sb(const u16* __restrict__ A,
                                               const u16* __restrict__ B,
                                               u16* __restrict__ Ct,
                                               const u16* __restrict__ Xt) {
  __shared__ __align__(16) u16 lds[8192];  // As 128x32 | Bs 128x32; reused as T 64x128
  u16* As = lds;
  u16* Bs = lds + 4096;
  const int t = threadIdx.x;
  const int wave = t >> 6, lane = t & 63;
  const int m0 = blockIdx.x << 7, c0 = blockIdx.y << 7;
  const int wm = (wave >> 1) << 6, wc = (wave & 1) << 6;
  const int q = lane >> 4, r16 = lane & 15;
  v4f acc[4][4];
  const v4f vz = {0.f, 0.f, 0.f, 0.f};
#pragma unroll
  for (int i = 0; i < 4; ++i)
#pragma unroll
    for (int j = 0; j < 4; ++j) acc[i][j] = vz;

  const int sr = t >> 2;             // 0..63
  const int sc = (t & 3) << 3;       // 0,8,16,24
  const u64 aoff = (u64)(m0 + sr) * NN + sc;
  const u64 boff = (u64)(c0 + sr) * NN + sc;
  const u64 rstep = (u64)64 * NN;
  u16* AsW = As + wave * 512;        // + lane*8 implicit in gld16
  u16* BsW = Bs + wave * 512;

  for (int k0 = 0; k0 < NN; k0 += 32) {
    gld16(A + aoff + k0, AsW);
    gld16(A + aoff + rstep + k0, AsW + 2048);
    gld16(B + boff + k0, BsW);
    gld16(B + boff + rstep + k0, BsW + 2048);
    __syncthreads();                 // drains vmcnt -> staged data visible
    v8s af[4], bf[4];
#pragma unroll
    for (int i = 0; i < 4; ++i)
      af[i] = *(const v8s*)(As + ((wm + i * 16 + r16) << 5) + (q << 3));
#pragma unroll
    for (int j = 0; j < 4; ++j)
      bf[j] = *(const v8s*)(Bs + ((wc + j * 16 + r16) << 5) + (q << 3));
#pragma unroll
    for (int i = 0; i < 4; ++i)
#pragma unroll
      for (int j = 0; j < 4; ++j)
        acc[i][j] = __builtin_amdgcn_mfma_f32_16x16x32_bf16(af[i], bf[j], acc[i][j], 0, 0, 0);
    __syncthreads();                 // readers done before next-iter overwrite
  }

  // two-half transposed epilogue through the same 16 KB LDS
  u16* T = lds;                      // [64 c][128 m]
  for (int h = 0; h < 2; ++h) {
    __syncthreads();
    if ((wave & 1) == h) {
#pragma unroll
      for (int i = 0; i < 4; ++i)
#pragma unroll
        for (int j = 0; j < 4; ++j) {
          const int cl = j * 16 + r16;             // 0..63 within half
          const int mm = wm + i * 16 + (q << 2);
          uint2 pv;
          pv.x = pk2(acc[i][j][0], acc[i][j][1]);
          pv.y = pk2(acc[i][j][2], acc[i][j][3]);
          *(uint2*)(T + (cl << 7) + mm) = pv;
        }
    }
    __syncthreads();
#pragma unroll
    for (int it = 0; it < 4; ++it) {
      const int flat = it * 256 + t;
      const int cl = flat >> 4;                    // 0..63
      const int seg = (flat & 15) << 3;
      const u64 gi = (u64)(c0 + h * 64 + cl) * NN + m0 + seg;
      union { uint4 v; u16 e[8]; } tv;
      tv.v = *(uint4*)(T + (cl << 7) + seg);
      if (Xt) {
        union { uint4 v; u16 e[8]; } xv, ov;
        xv.v = *(const uint4*)(Xt + gi);
#pragma unroll
        for (int s = 0; s < 8; ++s) ov.e[s] = f2b(2.f * b2f(tv.e[s]) - b2f(xv.e[s]));
        *(uint4*)(Ct + gi) = ov.v;
      } else {
        *(uint4*)(Ct + gi) = tv.v;
      }
    }
  }
}

// ---------------------------------------------------------------------------
// gemm_s (fallback if workspace too small for bf16 S): A f32, in-loop cvt.
// ---------------------------------------------------------------------------
__global__ __launch_bounds__(256) void gemm_s(const float* __restrict__ A,
                                              const u16* __restrict__ B,
                                              u16* __restrict__ Ct,
                                              const u16* __restrict__ Xt) {
  __shared__ __align__(16) u16 As[4096];
  __shared__ __align__(16) u16 Bs[4096];
  __shared__ __align__(16) u16 T[16384];
  const int t = threadIdx.x;
  const int wave = t >> 6, lane = t & 63;
  const int m0 = blockIdx.x << 7, c0 = blockIdx.y << 7;
  const int wm = (wave >> 1) << 6, wc = (wave & 1) << 6;
  const int q = lane >> 4, r16 = lane & 15;
  v4f acc[4][4];
  const v4f vz = {0.f, 0.f, 0.f, 0.f};
#pragma unroll
  for (int i = 0; i < 4; ++i)
#pragma unroll
    for (int j = 0; j < 4; ++j) acc[i][j] = vz;

  const int sr = t >> 2;
  const int sc = (t & 3) << 3;
  const u64 abase = (u64)(m0 + sr) * NN + sc;
  const u64 bbase = (u64)(c0 + sr) * NN + sc;
  const u64 rstep = (u64)64 * NN;
  u16* as0 = As + sr * 32 + sc;
  u16* as1 = As + (64 + sr) * 32 + sc;
  u16* bs0 = Bs + sr * 32 + sc;
  u16* bs1 = Bs + (64 + sr) * 32 + sc;

  for (int k0 = 0; k0 < NN; k0 += 32) {
    const float4 a0l = *(const float4*)(A + abase + k0);
    const float4 a0h = *(const float4*)(A + abase + k0 + 4);
    const float4 a1l = *(const float4*)(A + abase + rstep + k0);
    const float4 a1h = *(const float4*)(A + abase + rstep + k0 + 4);
    const uint4 b0 = *(const uint4*)(B + bbase + k0);
    const uint4 b1 = *(const uint4*)(B + bbase + rstep + k0);
    uint4 pa0, pa1;
    pa0.x = pk2(a0l.x, a0l.y); pa0.y = pk2(a0l.z, a0l.w);
    pa0.z = pk2(a0h.x, a0h.y); pa0.w = pk2(a0h.z, a0h.w);
    pa1.x = pk2(a1l.x, a1l.y); pa1.y = pk2(a1l.z, a1l.w);
    pa1.z = pk2(a1h.x, a1h.y); pa1.w = pk2(a1h.z, a1h.w);
    __syncthreads();
    *(uint4*)as0 = pa0;
    *(uint4*)as1 = pa1;
    *(uint4*)bs0 = b0;
    *(uint4*)bs1 = b1;
    __syncthreads();
    v8s af[4], bf[4];
#pragma unroll
    for (int i = 0; i < 4; ++i)
      af[i] = *(const v8s*)(As + ((wm + i * 16 + r16) << 5) + (q << 3));
#pragma unroll
    for (int j = 0; j < 4; ++j)
      bf[j] = *(const v8s*)(Bs + ((wc + j * 16 + r16) << 5) + (q << 3));
#pragma unroll
    for (int i = 0; i < 4; ++i)
#pragma unroll
      for (int j = 0; j < 4; ++j)
        acc[i][j] = __builtin_amdgcn_mfma_f32_16x16x32_bf16(af[i], bf[j], acc[i][j], 0, 0, 0);
  }
#pragma unroll
  for (int i = 0; i < 4; ++i)
#pragma unroll
    for (int j = 0; j < 4; ++j) {
      const int cl = wc + j * 16 + r16;
      const int mm = wm + i * 16 + (q << 2);
      uint2 pv;
      pv.x = pk2(acc[i][j][0], acc[i][j][1]);
      pv.y = pk2(acc[i][j][2], acc[i][j][3]);
      *(uint2*)(T + (cl << 7) + mm) = pv;
    }
  __syncthreads();
#pragma unroll
  for (int it = 0; it < 8; ++it) {
    const int flat = it * 256 + t;
    const int cl = flat >> 4;
    const int seg = (flat & 15) << 3;
    const u64 gi = (u64)(c0 + cl) * NN + m0 + seg;
    union { uint4 v; u16 e[8]; } tv;
    tv.v = *(uint4*)(T + (cl << 7) + seg);
    if (Xt) {
      union { uint4 v; u16 e[8]; } xv, ov;
      xv.v = *(const uint4*)(Xt + gi);
#pragma unroll
      for (int s = 0; s < 8; ++s) ov.e[s] = f2b(2.f * b2f(tv.e[s]) - b2f(xv.e[s]));
      *(uint4*)(Ct + gi) = ov.v;
    } else {
      *(uint4*)(Ct + gi) = tv.v;
    }
  }
}

// ---------------------------------------------------------------------------
// Projection: out[b*JSTR + j][n] = act( sum_k Wt[j][k] * F[row(k,b)][n] + b[j] )
// ---------------------------------------------------------------------------
template <int DP, int KTOT>
__global__ __launch_bounds__(256) void proj_k(const u16* __restrict__ Wt,
                                              const u16* __restrict__ F,
                                              const float* __restrict__ bias,
                                              u16* __restrict__ outp,
                                              const int JSTR, const int ACT) {
  __shared__ __align__(16) u16 As2[2048];  // 64 j x 32 k
  __shared__ __align__(16) u16 Bs2[4096];  // 32 k x 128 n
  const int t = threadIdx.x;
  const int wave = t >> 6, lane = t & 63;
  const int q = lane >> 4, r16 = lane & 15;
  const int n0 = blockIdx.x << 7;
  const int j0 = blockIdx.y << 6;
  const int b = blockIdx.z;
  v4f acc[4][2];
  const v4f vz = {0.f, 0.f, 0.f, 0.f};
#pragma unroll
  for (int i = 0; i < 4; ++i) { acc[i][0] = vz; acc[i][1] = vz; }

  const int ar = t >> 2, ac = (t & 3) << 3;
  const u64 wbase = (u64)(j0 + ar) * KTOT + ac;

  for (int k0 = 0; k0 < KTOT; k0 += 32) {
    const uint4 av = *(const uint4*)(Wt + wbase + k0);
    uint4 bv[2];
#pragma unroll
    for (int ci = 0; ci < 2; ++ci) {
      const int c = ci * 256 + t;
      const int kr = c >> 4;
      const int seg = (c & 15) << 3;
      const int kk = k0 + kr;
      const int i = kk / DP;
      const int d = kk - i * DP;
      bv[ci] = *(const uint4*)(F + ((u64)i * (BATCH * DP) + (u64)b * DP + d) * NN + n0 + seg);
    }
    __syncthreads();
    *(uint4*)(As2 + ar * 32 + ac) = av;
#pragma unroll
    for (int ci = 0; ci < 2; ++ci) {
      const int c = ci * 256 + t;
      const int kr = c >> 4;
      const int seg = (c & 15) << 3;
      *(uint4*)(Bs2 + (kr << 7) + seg) = bv[ci];
    }
    __syncthreads();
    v8s af[4], bf[2];
#pragma unroll
    for (int i = 0; i < 4; ++i)
      af[i] = *(const v8s*)(As2 + ((i * 16 + r16) << 5) + (q << 3));
#pragma unroll
    for (int jj = 0; jj < 2; ++jj) {
      const int nn = (wave << 5) + jj * 16 + r16;
      v8s v;
#pragma unroll
      for (int s = 0; s < 8; ++s) v[s] = (short)Bs2[(((q << 3) + s) << 7) + nn];
      bf[jj] = v;
    }
#pragma unroll
    for (int i = 0; i < 4; ++i)
#pragma unroll
      for (int jj = 0; jj < 2; ++jj)
        acc[i][jj] = __builtin_amdgcn_mfma_f32_16x16x32_bf16(af[i], bf[jj], acc[i][jj], 0, 0, 0);
  }
#pragma unroll
  for (int i = 0; i < 4; ++i)
#pragma unroll
    for (int jj = 0; jj < 2; ++jj)
#pragma unroll
      for (int r = 0; r < 4; ++r) {
        const int j = j0 + i * 16 + (q << 2) + r;
        const int n = n0 + (wave << 5) + jj * 16 + r16;
        float v = acc[i][jj][r] + bias[j];
        v = ACT ? (1.f - 2.f / (__expf(2.f * v) + 1.f)) : (1.f / (1.f + __expf(-v)));
        outp[((u64)b * JSTR + j) * NN + n] = f2b(v);
      }
}

// ---------------------------------------------------------------------------
__global__ __launch_bounds__(256) void repackW(const float* __restrict__ W, u16* __restrict__ Wt,
                                               const int D, const int DP, const int KTOT,
                                               const int J) {
  const int idx = blockIdx.x * 256 + threadIdx.x;
  if (idx >= J * KTOT) return;
  const int j = idx / KTOT, k = idx - j * KTOT;
  const int i = k / DP, d = k - i * DP;
  u16 v = 0;
  if (i < 5 && d < D) v = f2b(W[(i * D + d) * J + j]);
  Wt[idx] = v;
}

// ---------------------------------------------------------------------------
__global__ __launch_bounds__(256) void pack0(const float* __restrict__ x,
                                             const float* __restrict__ hid0,
                                             u16* __restrict__ F0) {
  __shared__ __align__(16) u16 Hs[64 * 72];
  const int b = blockIdx.y, n0 = blockIdx.x << 6, t = threadIdx.x;
  const int r = t >> 2, ds = t & 3;
  const float* hrow = hid0 + ((u64)b * NN + n0 + r) * 64;
#pragma unroll
  for (int c4 = 0; c4 < 4; ++c4) {
    const float4 v = *(const float4*)(hrow + ds * 16 + c4 * 4);
    uint2 p;
    p.x = pk2(v.x, v.y);
    p.y = pk2(v.z, v.w);
    *(uint2*)(Hs + r * 72 + ds * 16 + c4 * 4) = p;
  }
  __syncthreads();
#pragma unroll
  for (int c2 = 0; c2 < 2; ++c2) {
    union { uint4 v; u16 h[8]; } o;
#pragma unroll
    for (int s = 0; s < 8; ++s) o.h[s] = Hs[(ds * 16 + c2 * 8 + s) * 72 + r];
    *(uint4*)(F0 + ((u64)b * 72 + 1 + r) * NN + n0 + ds * 16 + c2 * 8) = o.v;
  }
  if (t < 64) {
    F0[(u64)b * 72 * NN + n0 + t] = f2b(x[(u64)b * NN + n0 + t]);
  } else if (t < 120) {
    const int tt = t - 64;
    const int row = 65 + (tt >> 3), seg = (tt & 7) << 3;
    uint4 z; z.x = z.y = z.z = z.w = 0;
    *(uint4*)(F0 + ((u64)b * 72 + row) * NN + n0 + seg) = z;
  }
}

// ---------------------------------------------------------------------------
__global__ __launch_bounds__(256) void pack1(const float* __restrict__ hid1,
                                             u16* __restrict__ F1) {
  __shared__ __align__(16) u16 Hs[64 * 72];
  const int b = blockIdx.y, n0 = blockIdx.x << 6, t = threadIdx.x;
  const int r = t >> 2, ds = t & 3;
  const float* hrow = hid1 + ((u64)b * NN + n0 + r) * 64;
#pragma unroll
  for (int c4 = 0; c4 < 4; ++c4) {
    const float4 v = *(const float4*)(hrow + ds * 16 + c4 * 4);
    uint2 p;
    p.x = pk2(v.x, v.y);
    p.y = pk2(v.z, v.w);
    *(uint2*)(Hs + r * 72 + ds * 16 + c4 * 4) = p;
  }
  __syncthreads();
#pragma unroll
  for (int c2 = 0; c2 < 2; ++c2) {
    union { uint4 v; u16 h[8]; } o;
#pragma unroll
    for (int s = 0; s < 8; ++s) o.h[s] = Hs[(ds * 16 + c2 * 8 + s) * 72 + r];
    *(uint4*)(F1 + ((u64)b * 128 + 64 + r) * NN + n0 + ds * 16 + c2 * 8) = o.v;
  }
}

// ---------------------------------------------------------------------------
__global__ __launch_bounds__(256) void candpack(const u16* __restrict__ G, u16* __restrict__ F,
                                                const int DP, const int OFF) {
  const int u = blockIdx.x * 256 + threadIdx.x;
  const int b = u >> 15;
  const int d = (u >> 9) & 63;
  const int seg = (u & 511) << 3;
  union { uint4 v; u16 h[8]; } g, f, o;
  g.v = *(const uint4*)(G + ((u64)b * 128 + d) * NN + seg);
  u16* fp = F + ((u64)b * DP + OFF + d) * NN + seg;
  f.v = *(const uint4*)fp;
#pragma unroll
  for (int s = 0; s < 8; ++s) o.h[s] = f2b(b2f(f.h[s]) * b2f(g.h[s]));
  *(uint4*)fp = o.v;
}

// ---------------------------------------------------------------------------
__global__ __launch_bounds__(256) void hnew_k(const u16* __restrict__ G,
                                              const float* __restrict__ hidL,
                                              u16* __restrict__ HnF,
                                              float* __restrict__ outH) {
  __shared__ __align__(16) float Hs[64 * 72];
  __shared__ __align__(16) float T2[64 * 72];
  const int b = blockIdx.y, n0 = blockIdx.x << 6, t = threadIdx.x;
  const int r = t >> 2, ds = t & 3;
  const float* hrow = hidL + ((u64)b * NN + n0 + r) * 64;
#pragma unroll
  for (int c4 = 0; c4 < 4; ++c4)
    *(float4*)(Hs + r * 72 + ds * 16 + c4 * 4) = *(const float4*)(hrow + ds * 16 + c4 * 4);
  __syncthreads();
#pragma unroll
  for (int c2 = 0; c2 < 2; ++c2) {
    const int ncol = ds * 16 + c2 * 8;
    union { uint4 v; u16 h[8]; } uv, cv, o;
    uv.v = *(const uint4*)(G + ((u64)b * 128 + 64 + r) * NN + n0 + ncol);
    cv.v = *(const uint4*)(G + ((u64)b * 128 + r) * NN + n0 + ncol);
#pragma unroll
    for (int s = 0; s < 8; ++s) {
      const int nl = ncol + s;
      const float uu = b2f(uv.h[s]);
      const float hh = Hs[nl * 72 + r];
      const float cc = b2f(cv.h[s]);
      const float v = uu * hh + (1.f - uu) * cc;
      o.h[s] = f2b(v);
      T2[nl * 72 + r] = v;
    }
    *(uint4*)(HnF + ((u64)b * 128 + r) * NN + n0 + ncol) = o.v;
  }
  __syncthreads();
  const int nl2 = t >> 2, dseg = (t & 3) << 4;
#pragma unroll
  for (int c4 = 0; c4 < 4; ++c4) {
    const float4 v = *(const float4*)(T2 + nl2 * 72 + dseg + c4 * 4);
    *(float4*)(outH + ((u64)b * NN + n0 + nl2) * 64 + dseg + c4 * 4) = v;
  }
}

// ---------------------------------------------------------------------------
__global__ __launch_bounds__(256) void predictk(const float* __restrict__ H1bnd,
                                                const float* __restrict__ Wp,
                                                const float* __restrict__ bp,
                                                float* __restrict__ outp) {
  __shared__ float w[64];
  __shared__ float bb;
  const int t = threadIdx.x;
  if (t < 64) w[t] = Wp[t];
  if (t == 64) bb = bp[0];
  __syncthreads();
  const int idx = blockIdx.x * 256 + t;
  const float* h = H1bnd + (u64)idx * 64;
  float acc = bb;
#pragma unroll
  for (int c4 = 0; c4 < 16; ++c4) {
    const float4 v = *(const float4*)(h + c4 * 4);
    acc += v.x * w[c4 * 4] + v.y * w[c4 * 4 + 1] + v.z * w[c4 * 4 + 2] + v.w * w[c4 * 4 + 3];
  }
  outp[idx] = acc;
}

static inline void launch_gemm(bool big, const float* Af, const u16* Ab,
                               const u16* B, u16* Ct, const u16* Xt,
                               dim3 g, hipStream_t s) {
  if (big) gemm_sb<<<g, 256, 0, s>>>(Ab, B, Ct, Xt);
  else     gemm_s<<<g, 256, 0, s>>>(Af, B, Ct, Xt);
}

extern "C" void kernel_launch(void* const* d_in, const int* in_sizes, int n_in,
                              void* d_out, int out_size, void* d_ws, size_t ws_size,
                              hipStream_t stream) {
  const float* X   = (const float*)d_in[0];
  const float* HID = (const float*)d_in[1];
  const float* Sf  = (const float*)d_in[2];
  const float* Sb  = (const float*)d_in[3];
  const float* Wg0 = (const float*)d_in[4];
  const float* bg0 = (const float*)d_in[5];
  const float* Wc0 = (const float*)d_in[6];
  const float* bc0 = (const float*)d_in[7];
  const float* Wg1 = (const float*)d_in[8];
  const float* bg1 = (const float*)d_in[9];
  const float* Wc1 = (const float*)d_in[10];
  const float* bc1 = (const float*)d_in[11];
  const float* Wp  = (const float*)d_in[12];
  const float* bp  = (const float*)d_in[13];
  float* OUT = (float*)d_out;
  char* ws = (char*)d_ws;

  // workspace map (bytes):
  //   F  : 20480 rows x 4096 bf16 = 167,772,160
  //   G  : 32 x 128 x 4096 bf16   =  33,554,432
  //  [Sfb, Sbb : 4096x4096 bf16 each = 33,554,432 ea]  (if ws_size allows)
  //   WT : repacked weights       =     393,216
  u16* F = (u16*)(ws);
  u16* G = (u16*)(ws + 167772160ull);
  const u64 NEED_BIG = 167772160ull + 33554432ull + 2ull * 33554432ull + 393216ull;
  const bool big = ws_size >= NEED_BIG;
  u16* Sfb = (u16*)(ws + 167772160ull + 33554432ull);
  u16* Sbb = Sfb + (u64)NN * NN;
  u16* WT = big ? (Sbb + (u64)NN * NN)
                : (u16*)(ws + 167772160ull + 33554432ull);
  u16* Wg0t = WT;                   // 128 x 384
  u16* Wc0t = Wg0t + 128 * 384;     // 64 x 384
  u16* Wg1t = Wc0t + 64 * 384;      // 128 x 640
  u16* Wc1t = Wg1t + 128 * 640;     // 64 x 640

  const float* HID1 = HID + (u64)32 * 4096 * 64;
  float* OUT_H0 = OUT + 131072;
  float* OUT_H1 = OUT + 131072 + 8388608;

  // zero the layer-0 K-padding region of F (rows 11520..13823), read by proj i=5
  hipMemsetAsync(ws + (u64)11520 * NN * 2, 0, (u64)2304 * NN * 2, stream);

  if (big) {
    cvtS<<<8192, 256, 0, stream>>>(Sf, Sfb);
    cvtS<<<8192, 256, 0, stream>>>(Sb, Sbb);
  }

  repackW<<<(128 * 384 + 255) / 256, 256, 0, stream>>>(Wg0, Wg0t, 65, 72, 384, 128);
  repackW<<<(64 * 384 + 255) / 256, 256, 0, stream>>>(Wc0, Wc0t, 65, 72, 384, 64);
  repackW<<<(128 * 640 + 255) / 256, 256, 0, stream>>>(Wg1, Wg1t, 128, 128, 640, 128);
  repackW<<<(64 * 640 + 255) / 256, 256, 0, stream>>>(Wc1, Wc1t, 128, 128, 640, 64);

  // ---------------- layer 0 (Dp=72, C=2304) ----------------
  pack0<<<dim3(64, 32), 256, 0, stream>>>(X, HID, F);
  const u64 R0 = (u64)2304 * NN;
  dim3 gs0(32, 18);
  launch_gemm(big, Sf, Sfb, F, F + R0, nullptr, gs0, stream);
  launch_gemm(big, Sb, Sbb, F, F + 3 * R0, nullptr, gs0, stream);
  launch_gemm(big, Sf, Sfb, F + R0, F + 2 * R0, F, gs0, stream);
  launch_gemm(big, Sb, Sbb, F + 3 * R0, F + 4 * R0, F, gs0, stream);
  proj_k<72, 384><<<dim3(32, 2, 32), 256, 0, stream>>>(Wg0t, F, bg0, G, 128, 0);
  candpack<<<4096, 256, 0, stream>>>(G, F, 72, 1);
  launch_gemm(big, Sf, Sfb, F, F + R0, nullptr, gs0, stream);
  launch_gemm(big, Sb, Sbb, F, F + 3 * R0, nullptr, gs0, stream);
  launch_gemm(big, Sf, Sfb, F + R0, F + 2 * R0, F, gs0, stream);
  launch_gemm(big, Sb, Sbb, F + 3 * R0, F + 4 * R0, F, gs0, stream);
  proj_k<72, 384><<<dim3(32, 1, 32), 256, 0, stream>>>(Wc0t, F, bc0, G, 128, 1);
  hnew_k<<<dim3(64, 32), 256, 0, stream>>>(G, HID, F, OUT_H0);

  // ---------------- layer 1 (Dp=128, C=4096) ----------------
  pack1<<<dim3(64, 32), 256, 0, stream>>>(HID1, F);
  const u64 R1 = (u64)4096 * NN;
  dim3 gs1(32, 32);
  launch_gemm(big, Sf, Sfb, F, F + R1, nullptr, gs1, stream);
  launch_gemm(big, Sb, Sbb, F, F + 3 * R1, nullptr, gs1, stream);
  launch_gemm(big, Sf, Sfb, F + R1, F + 2 * R1, F, gs1, stream);
  launch_gemm(big, Sb, Sbb, F + 3 * R1, F + 4 * R1, F, gs1, stream);
  proj_k<128, 640><<<dim3(32, 2, 32), 256, 0, stream>>>(Wg1t, F, bg1, G, 128, 0);
  candpack<<<4096, 256, 0, stream>>>(G, F, 128, 64);
  launch_gemm(big, Sf, Sfb, F, F + R1, nullptr, gs1, stream);
  launch_gemm(big, Sb, Sbb, F, F + 3 * R1, nullptr, gs1, stream);
  launch_gemm(big, Sf, Sfb, F + R1, F + 2 * R1, F, gs1, stream);
  launch_gemm(big, Sb, Sbb, F + 3 * R1, F + 4 * R1, F, gs1, stream);
  proj_k<128, 640><<<dim3(32, 1, 32), 256, 0, stream>>>(Wc1t, F, bc1, G, 128, 1);
  hnew_k<<<dim3(64, 32), 256, 0, stream>>>(G, HID1, F, OUT_H1);

  predictk<<<512, 256, 0, stream>>>(OUT_H1, Wp, bp, OUT);
}